// Round 1
// baseline (963.950 us; speedup 1.0000x reference)
//
#include <hip/hip_runtime.h>
#include <hip/hip_bf16.h>
#include <math.h>
#include <cstddef>

#define NN 20000
#define EE 320000
#define RR 8
#define PP 100000
#define NR (NN * RR)   // 160000 = 625*256

typedef __hip_bfloat16 bf16;
typedef __attribute__((ext_vector_type(8))) short short8;
typedef __attribute__((ext_vector_type(4))) float floatx4;

__device__ __forceinline__ float b2f(bf16 v) { return __bfloat162float(v); }
__device__ __forceinline__ bf16 f2b(float v) { return __float2bfloat16(v); }
__device__ __forceinline__ float bits2f(unsigned short u) {
  unsigned int i = ((unsigned int)u) << 16; float f; __builtin_memcpy(&f, &i, 4); return f;
}
__device__ __forceinline__ short f2bits(float f) {
  bf16 h = __float2bfloat16(f); short s; __builtin_memcpy(&s, &h, 2); return s;
}

// ---------------- CSR build ----------------
__global__ void hist_k(const int* __restrict__ dst, const int* __restrict__ et,
                       int* __restrict__ counts) {
  int e = blockIdx.x * 256 + threadIdx.x;
  if (e >= EE) return;
  atomicAdd(&counts[dst[e] * RR + et[e]], 1);
}

__global__ void scan1_k(const int* __restrict__ counts, int* __restrict__ prefix,
                        int* __restrict__ bsums) {
  __shared__ int tmp[256];
  int i = blockIdx.x * 256 + threadIdx.x;
  int v = counts[i];
  tmp[threadIdx.x] = v; __syncthreads();
  for (int off = 1; off < 256; off <<= 1) {
    int x = (threadIdx.x >= off) ? tmp[threadIdx.x - off] : 0;
    __syncthreads();
    tmp[threadIdx.x] += x;
    __syncthreads();
  }
  prefix[i] = tmp[threadIdx.x] - v;   // exclusive within block
  if (threadIdx.x == 255) bsums[blockIdx.x] = tmp[255];
}

__global__ void scan2_k(int* __restrict__ bsums, int nb) {
  __shared__ int tmp[256];
  __shared__ int carry;
  if (threadIdx.x == 0) carry = 0;
  __syncthreads();
  for (int base = 0; base < nb; base += 256) {
    int i = base + threadIdx.x;
    int v = (i < nb) ? bsums[i] : 0;
    tmp[threadIdx.x] = v; __syncthreads();
    for (int off = 1; off < 256; off <<= 1) {
      int x = (threadIdx.x >= off) ? tmp[threadIdx.x - off] : 0;
      __syncthreads();
      tmp[threadIdx.x] += x;
      __syncthreads();
    }
    int c = carry;
    if (i < nb) bsums[i] = c + tmp[threadIdx.x] - v;  // exclusive
    __syncthreads();
    if (threadIdx.x == 255) carry = c + tmp[255];
    __syncthreads();
  }
}

__global__ void scan3_k(int* __restrict__ prefix, const int* __restrict__ bsums) {
  int i = blockIdx.x * 256 + threadIdx.x;
  prefix[i] += bsums[blockIdx.x];
}

__global__ void scatter_k(const int* __restrict__ src, const int* __restrict__ dst,
                          const int* __restrict__ et, const int* __restrict__ segstart,
                          int* __restrict__ cursor, int* __restrict__ ssrc) {
  int e = blockIdx.x * 256 + threadIdx.x;
  if (e >= EE) return;
  int s = dst[e] * RR + et[e];
  int pos = atomicAdd(&cursor[s], 1);
  ssrc[segstart[s] + pos] = src[e];
}

// ---------------- small prep kernels ----------------
__global__ void cvt_bf16_k(const float* __restrict__ in, bf16* __restrict__ out, int n) {
  int i = blockIdx.x * 256 + threadIdx.x;
  if (i < n) out[i] = f2b(in[i]);
}

__global__ void softmax4_k(const float* r0, const float* r1, const float* r2,
                           const float* r3, float* __restrict__ a) {
  if (threadIdx.x == 0) {
    const float* rs[4] = {r0, r1, r2, r3};
    for (int l = 0; l < 4; ++l) {
      float mx = -1e30f;
      for (int i = 0; i < RR; ++i) mx = fmaxf(mx, rs[l][i]);
      float e[RR]; float s = 0.f;
      for (int i = 0; i < RR; ++i) { e[i] = expf(rs[l][i] - mx); s += e[i]; }
      for (int i = 0; i < RR; ++i) a[l * RR + i] = e[i] / s;
    }
  }
}

__global__ void transpose_k(const float* __restrict__ in, bf16* __restrict__ out,
                            int rows, int cols) {
  int idx = blockIdx.x * 256 + threadIdx.x;
  if (idx >= rows * cols) return;
  int r = idx / cols, c = idx - r * cols;
  out[(size_t)c * rows + r] = f2b(in[idx]);
}

// Wt[o, r*ic + k] = a[r] * sum_b att[r,b]*basis[b,k,o];  Wt[o, 8*ic + k] = root[k,o]
__global__ void prep_w_k(const float* __restrict__ basis, const float* __restrict__ att,
                         const float* __restrict__ root, const float* __restrict__ a,
                         bf16* __restrict__ Wt, int ic, int icsh, int oc) {
  int idx = blockIdx.x * 256 + threadIdx.x;
  int cols = 9 * ic;
  if (idx >= cols * oc) return;
  int o = idx / cols;
  int col = idx - o * cols;
  int r = col >> icsh;
  int k = col & (ic - 1);
  float val;
  if (r < RR) {
    float acc = 0.f;
    for (int bb = 0; bb < RR; ++bb)
      acc += att[r * RR + bb] * basis[((size_t)bb * ic + k) * oc + o];
    val = a[r] * acc;
  } else {
    val = root[(size_t)k * oc + o];
  }
  Wt[(size_t)o * cols + col] = f2b(val);
}

// ---------------- aggregation (segment sums + self row) ----------------
__global__ __launch_bounds__(256) void aggregate_k(
    const bf16* __restrict__ h, const int* __restrict__ segstart,
    const int* __restrict__ counts, const int* __restrict__ ssrc,
    bf16* __restrict__ agg, int ic, int tpnsh) {
  int tpn = 1 << tpnsh;           // threads per node = ic/8
  int npb = 256 >> tpnsh;         // nodes per block
  int local = threadIdx.x >> tpnsh;
  int n = blockIdx.x * npb + local;
  if (n >= NN) return;
  int cbase = (threadIdx.x & (tpn - 1)) * 8;
  size_t rowoff = (size_t)n * (9 * ic);
  for (int r = 0; r < RR; ++r) {
    int s = n * RR + r;
    int st = segstart[s];
    int cnt = counts[s];
    float a[8] = {0.f, 0.f, 0.f, 0.f, 0.f, 0.f, 0.f, 0.f};
    for (int i = 0; i < cnt; ++i) {
      int src = ssrc[st + i];
      short8 v = *(const short8*)(h + (size_t)src * ic + cbase);
#pragma unroll
      for (int j = 0; j < 8; ++j) a[j] += bits2f((unsigned short)v[j]);
    }
    short8 o;
#pragma unroll
    for (int j = 0; j < 8; ++j) o[j] = f2bits(a[j]);
    *(short8*)(agg + rowoff + r * ic + cbase) = o;
  }
  // self row (for folded root GEMM)
  *(short8*)(agg + rowoff + 8 * ic + cbase) =
      *(const short8*)(h + (size_t)n * ic + cbase);
}

// ---------------- bf16 MFMA GEMM: C[M,N] = A[M,K] @ Wt[N,K]^T ----------------
__global__ __launch_bounds__(256) void gemm_bf16_k(
    const bf16* __restrict__ A, const bf16* __restrict__ Wt,
    float* __restrict__ Cf, bf16* __restrict__ Cb,
    const float* __restrict__ bias, int M, int N, int K) {
  __shared__ __align__(16) bf16 As[64][88];  // stride 88 bf16 = 176B: 16B-aligned, 2-way max bank alias
  __shared__ __align__(16) bf16 Ws[64][88];
  const int m0 = blockIdx.x * 64;
  const int n0 = blockIdx.y * 64;
  const int tid = threadIdx.x;
  const int wave = tid >> 6, lane = tid & 63;
  const int quad = lane >> 4, l16 = lane & 15;
  const int wm = (wave >> 1) * 32, wn = (wave & 1) * 32;
  floatx4 acc00 = {0.f, 0.f, 0.f, 0.f};
  floatx4 acc01 = acc00, acc10 = acc00, acc11 = acc00;

  const int r0 = tid >> 3;          // 0..31
  const int cc = (tid & 7) * 8;     // col chunk within 64
  for (int k0 = 0; k0 < K; k0 += 64) {
    {
      int gr = m0 + r0;
      short8 v = {0, 0, 0, 0, 0, 0, 0, 0};
      if (gr < M) v = *(const short8*)(A + (size_t)gr * K + (k0 + cc));
      *(short8*)(&As[r0][cc]) = v;
      int gr2 = m0 + r0 + 32;
      short8 v2 = {0, 0, 0, 0, 0, 0, 0, 0};
      if (gr2 < M) v2 = *(const short8*)(A + (size_t)gr2 * K + (k0 + cc));
      *(short8*)(&As[r0 + 32][cc]) = v2;
      *(short8*)(&Ws[r0][cc]) = *(const short8*)(Wt + (size_t)(n0 + r0) * K + (k0 + cc));
      *(short8*)(&Ws[r0 + 32][cc]) = *(const short8*)(Wt + (size_t)(n0 + r0 + 32) * K + (k0 + cc));
    }
    __syncthreads();
#pragma unroll
    for (int kk = 0; kk < 64; kk += 32) {
      short8 a0 = *(const short8*)(&As[wm + l16][kk + quad * 8]);
      short8 a1 = *(const short8*)(&As[wm + 16 + l16][kk + quad * 8]);
      short8 b0 = *(const short8*)(&Ws[wn + l16][kk + quad * 8]);
      short8 b1 = *(const short8*)(&Ws[wn + 16 + l16][kk + quad * 8]);
      acc00 = __builtin_amdgcn_mfma_f32_16x16x32_bf16(a0, b0, acc00, 0, 0, 0);
      acc01 = __builtin_amdgcn_mfma_f32_16x16x32_bf16(a0, b1, acc01, 0, 0, 0);
      acc10 = __builtin_amdgcn_mfma_f32_16x16x32_bf16(a1, b0, acc10, 0, 0, 0);
      acc11 = __builtin_amdgcn_mfma_f32_16x16x32_bf16(a1, b1, acc11, 0, 0, 0);
    }
    __syncthreads();
  }
  floatx4 accs[2][2] = {{acc00, acc01}, {acc10, acc11}};
#pragma unroll
  for (int i = 0; i < 2; ++i)
#pragma unroll
    for (int j = 0; j < 2; ++j)
#pragma unroll
      for (int r = 0; r < 4; ++r) {
        int row = m0 + wm + i * 16 + quad * 4 + r;   // C/D: row = quad*4+reg
        int col = n0 + wn + j * 16 + l16;            //      col = lane&15
        if (row < M) {
          float v = accs[i][j][r];
          if (bias) v += bias[col];
          if (Cf) Cf[(size_t)row * N + col] = v;
          else    Cb[(size_t)row * N + col] = f2b(v);
        }
      }
}

// ---------------- LN (+residual, +gelu) for conv layers ----------------
__global__ __launch_bounds__(256) void ln_conv_k(
    const float* __restrict__ conv, const float* __restrict__ resf,
    const bf16* __restrict__ resb, const float* __restrict__ g,
    const float* __restrict__ b, bf16* __restrict__ out,
    float* __restrict__ zout, int oc, int do_gelu) {
  int wave = threadIdx.x >> 6, lane = threadIdx.x & 63;
  int row = blockIdx.x * 4 + wave;
  if (row >= NN) return;
  int ne = oc >> 6;  // 4 or 2
  float v[4];
  float s = 0.f, s2 = 0.f;
  for (int i = 0; i < ne; ++i) {
    v[i] = conv[(size_t)row * oc + i * 64 + lane];
    s += v[i]; s2 += v[i] * v[i];
  }
  for (int off = 32; off; off >>= 1) { s += __shfl_xor(s, off); s2 += __shfl_xor(s2, off); }
  float m = s / oc;
  float var = s2 / oc - m * m;
  float rs = rsqrtf(var + 1e-5f);
  for (int i = 0; i < ne; ++i) {
    int c = i * 64 + lane;
    float y = (v[i] - m) * rs * g[c] + b[c];
    float rr = resf ? resf[(size_t)row * oc + c] : b2f(resb[(size_t)row * oc + c]);
    y += rr;
    if (do_gelu) y = 0.5f * y * (1.f + erff(y * 0.7071067811865476f));
    out[(size_t)row * oc + c] = f2b(y);
    if (zout) zout[(size_t)row * oc + c] = y;
  }
}

// ---------------- decoder elementwise ----------------
__global__ __launch_bounds__(256) void pe_k(const bf16* __restrict__ z,
                                            const int* __restrict__ pairs,
                                            bf16* __restrict__ pe) {
  int wave = threadIdx.x >> 6, lane = threadIdx.x & 63;
  int p = blockIdx.x * 4 + wave;
  if (p >= PP) return;
  int gi = pairs[p], gj = pairs[PP + p];
  for (int t = lane; t < 128; t += 64) {
    float a = b2f(z[(size_t)gi * 128 + t]);
    float b = b2f(z[(size_t)gj * 128 + t]);
    size_t base = (size_t)p * 384;
    pe[base + t] = f2b(a + b);
    pe[base + 128 + t] = f2b(a * b);
    pe[base + 256 + t] = f2b(fabsf(a - b));
  }
}

__global__ __launch_bounds__(256) void ln_act_k(bf16* __restrict__ d,
                                                const float* __restrict__ g,
                                                const float* __restrict__ b,
                                                int width, int rows) {
  int wave = threadIdx.x >> 6, lane = threadIdx.x & 63;
  int row = blockIdx.x * 4 + wave;
  if (row >= rows) return;
  int ne = width >> 6;  // 4,2,1
  float v[4];
  float s = 0.f, s2 = 0.f;
  for (int i = 0; i < ne; ++i) {
    v[i] = b2f(d[(size_t)row * width + i * 64 + lane]);
    s += v[i]; s2 += v[i] * v[i];
  }
  for (int off = 32; off; off >>= 1) { s += __shfl_xor(s, off); s2 += __shfl_xor(s2, off); }
  float m = s / width;
  float var = s2 / width - m * m;
  float rs = rsqrtf(var + 1e-5f);
  for (int i = 0; i < ne; ++i) {
    int c = i * 64 + lane;
    float y = (v[i] - m) * rs * g[c] + b[c];
    y = 0.5f * y * (1.f + erff(y * 0.7071067811865476f));
    d[(size_t)row * width + c] = f2b(y);
  }
}

__global__ __launch_bounds__(256) void logits_k(const bf16* __restrict__ d2,
                                                const float* __restrict__ w3,
                                                const float* __restrict__ b3,
                                                float* __restrict__ out) {
  int wave = threadIdx.x >> 6, lane = threadIdx.x & 63;
  int p = blockIdx.x * 4 + wave;
  if (p >= PP) return;
  float v = b2f(d2[(size_t)p * 64 + lane]) * w3[lane];
  for (int off = 32; off; off >>= 1) v += __shfl_xor(v, off);
  if (lane == 0) out[p] = v + b3[0];
}

// ---------------- host ----------------
extern "C" void kernel_launch(void* const* d_in, const int* in_sizes, int n_in,
                              void* d_out, int out_size, void* d_ws, size_t ws_size,
                              hipStream_t stream) {
  auto cdiv = [](int a, int b) { return (a + b - 1) / b; };

  const float* x = (const float*)d_in[0];
  const int* ei = (const int*)d_in[1];    // [2,E]: src = ei, dst = ei+E
  const int* et = (const int*)d_in[2];
  const int* gp = (const int*)d_in[3];    // [2,P]
  const float *basis[4], *att[4], *root[4], *relatt[4], *gln[4], *bln[4];
  for (int l = 0; l < 4; ++l) {
    basis[l]  = (const float*)d_in[4 + 6 * l];
    att[l]    = (const float*)d_in[5 + 6 * l];
    root[l]   = (const float*)d_in[6 + 6 * l];
    relatt[l] = (const float*)d_in[7 + 6 * l];
    gln[l]    = (const float*)d_in[8 + 6 * l];
    bln[l]    = (const float*)d_in[9 + 6 * l];
  }
  const float* res0 = (const float*)d_in[28];
  const float* res3 = (const float*)d_in[29];
  const float* dW0 = (const float*)d_in[30]; const float* db0 = (const float*)d_in[31];
  const float* dg0 = (const float*)d_in[32]; const float* dbb0 = (const float*)d_in[33];
  const float* dW1 = (const float*)d_in[34]; const float* db1 = (const float*)d_in[35];
  const float* dg1 = (const float*)d_in[36]; const float* dbb1 = (const float*)d_in[37];
  const float* dW2 = (const float*)d_in[38]; const float* db2 = (const float*)d_in[39];
  const float* dg2 = (const float*)d_in[40]; const float* dbb2 = (const float*)d_in[41];
  const float* dW3 = (const float*)d_in[42]; const float* db3 = (const float*)d_in[43];

  char* base = (char*)d_ws;
  size_t off = 0;
  auto alloc = [&](size_t bytes) -> char* {
    char* p = base + off;
    off += (bytes + 255) & ~(size_t)255;
    return p;
  };
  bf16* X16 = (bf16*)alloc((size_t)NN * 128 * 2);
  bf16* HA  = (bf16*)alloc((size_t)NN * 256 * 2);
  bf16* HB  = (bf16*)alloc((size_t)NN * 256 * 2);
  float* CONV = (float*)alloc((size_t)NN * 256 * 4);
  float* RESB = (float*)alloc((size_t)NN * 256 * 4);
  bf16* WT    = (bf16*)alloc((size_t)589824 * 2);
  bf16* RES0T = (bf16*)alloc((size_t)32768 * 2);
  bf16* RES3T = (bf16*)alloc((size_t)32768 * 2);
  bf16* DW0T  = (bf16*)alloc((size_t)98304 * 2);
  bf16* DW1T  = (bf16*)alloc((size_t)32768 * 2);
  bf16* DW2T  = (bf16*)alloc((size_t)8192 * 2);
  float* ASOFT = (float*)alloc(32 * 4);
  int* COUNTS = (int*)alloc((size_t)NR * 4);
  int* SEG    = (int*)alloc((size_t)NR * 4);
  int* CUR    = (int*)alloc((size_t)NR * 4);
  int* BS     = (int*)alloc(1024 * 4);
  int* SSRC   = (int*)alloc((size_t)EE * 4);
  char* BIG = alloc(128000000);     // overlay: agg [N,9*256]bf16 (92.16MB) | pe(76.8MB)+d0(51.2MB)
  bf16* AGG = (bf16*)BIG;
  bf16* PE  = (bf16*)BIG;
  bf16* D0  = (bf16*)(BIG + 76800000);
  bf16* D1  = (bf16*)alloc((size_t)PP * 128 * 2);
  bf16* D2  = (bf16*)alloc((size_t)PP * 64 * 2);
  (void)ws_size; (void)in_sizes; (void)n_in; (void)out_size;

  float* out_logits = (float*)d_out;
  float* out_z = (float*)d_out + PP;

  // --- CSR build (reused by all 4 layers) ---
  hipMemsetAsync(COUNTS, 0, (size_t)NR * 4, stream);
  hipMemsetAsync(CUR, 0, (size_t)NR * 4, stream);
  hist_k<<<cdiv(EE, 256), 256, 0, stream>>>(ei + EE, et, COUNTS);
  scan1_k<<<NR / 256, 256, 0, stream>>>(COUNTS, SEG, BS);
  scan2_k<<<1, 256, 0, stream>>>(BS, NR / 256);
  scan3_k<<<NR / 256, 256, 0, stream>>>(SEG, BS);
  scatter_k<<<cdiv(EE, 256), 256, 0, stream>>>(ei, ei + EE, et, SEG, CUR, SSRC);

  // --- weight prep ---
  cvt_bf16_k<<<cdiv(NN * 128, 256), 256, 0, stream>>>(x, X16, NN * 128);
  softmax4_k<<<1, 64, 0, stream>>>(relatt[0], relatt[1], relatt[2], relatt[3], ASOFT);
  transpose_k<<<cdiv(128 * 256, 256), 256, 0, stream>>>(res0, RES0T, 128, 256);
  transpose_k<<<cdiv(256 * 128, 256), 256, 0, stream>>>(res3, RES3T, 256, 128);
  transpose_k<<<cdiv(384 * 256, 256), 256, 0, stream>>>(dW0, DW0T, 384, 256);
  transpose_k<<<cdiv(256 * 128, 256), 256, 0, stream>>>(dW1, DW1T, 256, 128);
  transpose_k<<<cdiv(128 * 64, 256), 256, 0, stream>>>(dW2, DW2T, 128, 64);

  // --- layer 0: ic=128, oc=256, residual = x @ res0 ---
  prep_w_k<<<cdiv(9 * 128 * 256, 256), 256, 0, stream>>>(basis[0], att[0], root[0], ASOFT + 0, WT, 128, 7, 256);
  aggregate_k<<<cdiv(NN, 16), 256, 0, stream>>>(X16, SEG, COUNTS, SSRC, AGG, 128, 4);
  gemm_bf16_k<<<dim3(cdiv(NN, 64), 4), 256, 0, stream>>>(AGG, WT, CONV, nullptr, nullptr, NN, 256, 1152);
  gemm_bf16_k<<<dim3(cdiv(NN, 64), 4), 256, 0, stream>>>(X16, RES0T, RESB, nullptr, nullptr, NN, 256, 128);
  ln_conv_k<<<cdiv(NN, 4), 256, 0, stream>>>(CONV, RESB, nullptr, gln[0], bln[0], HA, nullptr, 256, 1);

  // --- layer 1: ic=256, oc=256, residual = h_in ---
  prep_w_k<<<cdiv(9 * 256 * 256, 256), 256, 0, stream>>>(basis[1], att[1], root[1], ASOFT + 8, WT, 256, 8, 256);
  aggregate_k<<<cdiv(NN, 8), 256, 0, stream>>>(HA, SEG, COUNTS, SSRC, AGG, 256, 5);
  gemm_bf16_k<<<dim3(cdiv(NN, 64), 4), 256, 0, stream>>>(AGG, WT, CONV, nullptr, nullptr, NN, 256, 2304);
  ln_conv_k<<<cdiv(NN, 4), 256, 0, stream>>>(CONV, nullptr, HA, gln[1], bln[1], HB, nullptr, 256, 1);

  // --- layer 2 ---
  prep_w_k<<<cdiv(9 * 256 * 256, 256), 256, 0, stream>>>(basis[2], att[2], root[2], ASOFT + 16, WT, 256, 8, 256);
  aggregate_k<<<cdiv(NN, 8), 256, 0, stream>>>(HB, SEG, COUNTS, SSRC, AGG, 256, 5);
  gemm_bf16_k<<<dim3(cdiv(NN, 64), 4), 256, 0, stream>>>(AGG, WT, CONV, nullptr, nullptr, NN, 256, 2304);
  ln_conv_k<<<cdiv(NN, 4), 256, 0, stream>>>(CONV, nullptr, HB, gln[2], bln[2], HA, nullptr, 256, 1);

  // --- layer 3: oc=128, residual = h_in @ res3, no gelu; writes z ---
  prep_w_k<<<cdiv(9 * 256 * 128, 256), 256, 0, stream>>>(basis[3], att[3], root[3], ASOFT + 24, WT, 256, 8, 128);
  aggregate_k<<<cdiv(NN, 8), 256, 0, stream>>>(HA, SEG, COUNTS, SSRC, AGG, 256, 5);
  gemm_bf16_k<<<dim3(cdiv(NN, 64), 2), 256, 0, stream>>>(AGG, WT, CONV, nullptr, nullptr, NN, 128, 2304);
  gemm_bf16_k<<<dim3(cdiv(NN, 64), 2), 256, 0, stream>>>(HA, RES3T, RESB, nullptr, nullptr, NN, 128, 256);
  ln_conv_k<<<cdiv(NN, 4), 256, 0, stream>>>(CONV, RESB, nullptr, gln[3], bln[3], HB, out_z, 128, 0);

  // --- decoder ---
  pe_k<<<cdiv(PP, 4), 256, 0, stream>>>(HB, gp, PE);
  gemm_bf16_k<<<dim3(cdiv(PP, 64), 4), 256, 0, stream>>>(PE, DW0T, nullptr, D0, db0, PP, 256, 384);
  ln_act_k<<<cdiv(PP, 4), 256, 0, stream>>>(D0, dg0, dbb0, 256, PP);
  gemm_bf16_k<<<dim3(cdiv(PP, 64), 2), 256, 0, stream>>>(D0, DW1T, nullptr, D1, db1, PP, 128, 256);
  ln_act_k<<<cdiv(PP, 4), 256, 0, stream>>>(D1, dg1, dbb1, 128, PP);
  gemm_bf16_k<<<dim3(cdiv(PP, 64), 1), 256, 0, stream>>>(D1, DW2T, nullptr, D2, db2, PP, 64, 128);
  ln_act_k<<<cdiv(PP, 4), 256, 0, stream>>>(D2, dg2, dbb2, 64, PP);
  logits_k<<<cdiv(PP, 4), 256, 0, stream>>>(D2, dW3, db3, out_logits);
}